// Round 8
// baseline (1064.394 us; speedup 1.0000x reference)
//
#include <hip/hip_runtime.h>
#include <cstddef>
#include <cstdint>

// SNN: 4x (Linear + LIF). GEMMs on bf16 MFMA via EXACT 3-term splitting with
// scale-segregated accumulation (same per-acc MFMA chain order as R5-R7 ->
// bit-identical numerics). gemm256 v3 (L0/L1): 256x256 tile, 8 waves, BK=32,
// 4-deep LDS ring (128KB) -> prefetch issued 3 K-tiles ahead (~900+ cyc,
// covers HBM latency), ONE vmcnt(8)+barrier per K-tile, setprio MFMA
// clusters, XCD swizzle, pre-swizzled operands (0 bank conflicts).
// L2/L3 keep the 128-tile gemm_seg.

#define BETA 0.95f

static constexpr int B_ = 128;
static constexpr int T_ = 64;
static constexpr int M_ = B_ * T_;       // 8192 rows
static constexpr int NOUT = 128;

typedef __bf16 bf16x8 __attribute__((ext_vector_type(8)));
typedef float f32x4 __attribute__((ext_vector_type(4)));
typedef ushort u16x8 __attribute__((ext_vector_type(8)));

__device__ __forceinline__ ushort f32_bf16_rne(float f) {
  uint32_t u = __float_as_uint(f);
  uint32_t r = u + 0x7FFFu + ((u >> 16) & 1u);
  return (ushort)(r >> 16);
}
__device__ __forceinline__ float bf16_f32(ushort h) {
  return __uint_as_float(((uint32_t)h) << 16);
}

// ---------------------------------------------------------------------------
// fp32 -> 3 bf16 exact split, written at swizzled slot positions.
// mode 0 (128-tile kernel): stored slot = slot ^ (row&7)           [3-bit XOR]
// mode 1 (256-tile kernel): stored slot = (slot&4)|((slot&3)^((row>>1)&3))
// ---------------------------------------------------------------------------
__global__ __launch_bounds__(256) void split3_swz(
    const float* __restrict__ S, ushort* __restrict__ o1,
    ushort* __restrict__ o2, ushort* __restrict__ o3,
    int K, int nslots, int mode)
{
  int g = blockIdx.x * 256 + threadIdx.x;
  if (g >= nslots) return;
  int spr = K >> 3;
  int row = g / spr;
  int sl = g - row * spr;
  int kb = sl >> 3;
  int slot = sl & 7;
  int pslot = mode ? ((slot & 4) | ((slot & 3) ^ ((row >> 1) & 3)))
                   : (slot ^ (row & 7));
  const float* src = S + (size_t)row * K + (kb << 6) + (slot << 3);
  size_t dst = (size_t)row * K + (kb << 6) + (pslot << 3);
  u16x8 v1, v2, v3;
#pragma unroll
  for (int i = 0; i < 8; ++i) {
    float f = src[i];
    ushort h1 = f32_bf16_rne(f);
    float r = f - bf16_f32(h1);
    ushort h2 = f32_bf16_rne(r);
    float r2 = r - bf16_f32(h2);
    ushort h3 = f32_bf16_rne(r2);
    v1[i] = h1; v2[i] = h2; v3[i] = h3;
  }
  *reinterpret_cast<u16x8*>(o1 + dst) = v1;
  *reinterpret_cast<u16x8*>(o2 + dst) = v2;
  *reinterpret_cast<u16x8*>(o3 + dst) = v3;
}

// ---------------------------------------------------------------------------
// R5 kernel (kept for L2/L3): 128x128 tile, BK=64, 4 waves, 2-barrier K-step.
// Operands use mode-0 (3-bit) swizzle.
// ---------------------------------------------------------------------------
__global__ __launch_bounds__(256) void gemm_seg(
    const ushort* __restrict__ A0, const ushort* __restrict__ A1,
    const ushort* __restrict__ A2,
    const ushort* __restrict__ B0, const ushort* __restrict__ B1,
    const ushort* __restrict__ B2,
    int P, int apack, int bpack, int K, int N, int accum,
    float* __restrict__ C)
{
  __shared__ ushort As[128 * 64];
  __shared__ ushort Bs[128 * 64];

  const int tid = threadIdx.x;
  const int lane = tid & 63;
  const int wid = tid >> 6;
  const int wr = wid >> 1, wc = wid & 1;
  const int lane15 = lane & 15;
  const int lhi = lane >> 4;
  const int rswz = lane15 & 7;
  const int lrow = lane >> 3, lslot = lane & 7;

  int nwg = gridDim.x * gridDim.y;
  int bid = blockIdx.y * gridDim.x + blockIdx.x;
  int cpx = nwg >> 3;
  int sw = (bid & 7) * cpx + (bid >> 3);
  int bx = sw % gridDim.x, by = sw / gridDim.x;
  const int bm = by * 128, bn = bx * 128;

  f32x4 acc[4][4];
#pragma unroll
  for (int i = 0; i < 4; ++i)
#pragma unroll
    for (int j = 0; j < 4; ++j)
      acc[i][j] = (f32x4){0.f, 0.f, 0.f, 0.f};

  const bool isA = (wid < 2);
  ushort* lbase = isA ? As : Bs;
  const int rowbase0 = isA ? bm : bn;
  const int chunk0 = (wid & 1) * 8;

  for (int p = 0; p < P; ++p) {
    int ai = (apack >> (2 * p)) & 3;
    int bi = (bpack >> (2 * p)) & 3;
    const ushort* Ap = ai == 0 ? A0 : (ai == 1 ? A1 : A2);
    const ushort* Bp = bi == 0 ? B0 : (bi == 1 ? B1 : B2);
    const ushort* gsrc = isA ? Ap : Bp;
    for (int k0 = 0; k0 < K; k0 += 64) {
      __syncthreads();
#pragma unroll
      for (int c = 0; c < 8; ++c) {
        int chunk = chunk0 + c;
        int row = chunk * 8 + lrow;
        const ushort* g = gsrc + (size_t)(rowbase0 + row) * K + k0 + (lslot << 3);
        __builtin_amdgcn_global_load_lds(
            (const __attribute__((address_space(1))) void*)(g),
            (__attribute__((address_space(3))) void*)(lbase + chunk * 512),
            16, 0, 0);
      }
      __syncthreads();
#pragma unroll
      for (int kk = 0; kk < 2; ++kk) {
        int sp = ((kk << 2) | lhi) ^ rswz;
        bf16x8 af[4], bg[4];
#pragma unroll
        for (int i = 0; i < 4; ++i)
          af[i] = *(const bf16x8*)(As + (wr * 64 + i * 16 + lane15) * 64 + sp * 8);
#pragma unroll
        for (int j = 0; j < 4; ++j)
          bg[j] = *(const bf16x8*)(Bs + (wc * 64 + j * 16 + lane15) * 64 + sp * 8);
#pragma unroll
        for (int i = 0; i < 4; ++i)
#pragma unroll
          for (int j = 0; j < 4; ++j)
            acc[i][j] = __builtin_amdgcn_mfma_f32_16x16x32_bf16(
                af[i], bg[j], acc[i][j], 0, 0, 0);
      }
    }
  }

#pragma unroll
  for (int j = 0; j < 4; ++j) {
    int col = bn + wc * 64 + j * 16 + lane15;
#pragma unroll
    for (int i = 0; i < 4; ++i) {
      f32x4 v = acc[i][j];
      int r0 = bm + wr * 64 + i * 16 + lhi * 4;
      if (accum) {
#pragma unroll
        for (int r = 0; r < 4; ++r) {
          size_t idx = (size_t)(r0 + r) * N + col;
          C[idx] = C[idx] + v[r];
        }
      } else {
#pragma unroll
        for (int r = 0; r < 4; ++r)
          C[(size_t)(r0 + r) * N + col] = v[r];
      }
    }
  }
}

// ---------------------------------------------------------------------------
// gemm256 v3: 256x256 tile, 8 waves (2Mx4N), K=2048, P chained passes.
// BK=32, 4-deep LDS ring: slot s holds K-tile t (t&3==s): A[256][32] at
// s*16KB, B[256][32] at 64KB + s*16KB. Per K-tile each thread stages 4 loads
// (2A+2B) for tile t+3 (dummy-clamped) -> prefetch distance 3 tiles.
// One vmcnt(8) + s_barrier per K-tile: oldest 4 outstanding = tile t+1.
// Ring safety: staged slot (t+3)&3 == (t-1)&3, consumed before last barrier.
// Per-acc MFMA chain = (pass, k ascending by 32) -> identical to gemm_seg.
// ---------------------------------------------------------------------------
__global__ __launch_bounds__(512) void gemm256(
    const ushort* __restrict__ A0, const ushort* __restrict__ A1,
    const ushort* __restrict__ A2,
    const ushort* __restrict__ B0, const ushort* __restrict__ B1,
    const ushort* __restrict__ B2,
    int P, int apack, int bpack, int N, int accum,
    float* __restrict__ C)
{
  __shared__ __align__(16) ushort lds[65536];  // A ring: [0,32768), B ring: [32768,65536)

  const int tid = threadIdx.x;
  const int lane = tid & 63;
  const int wid = tid >> 6;        // 0..7
  const int wm = wid >> 2;         // 0..1  (M half)
  const int wn = wid & 3;          // 0..3  (N quarter)
  const int lane15 = lane & 15;
  const int lhi = lane >> 4;       // 0..3
  const int s2 = lhi ^ ((lane15 >> 1) & 3);  // stored granule within k-tile

  // bijective XCD swizzle (grids are multiples of 8)
  int nwg = gridDim.x * gridDim.y;
  int bid = blockIdx.y * gridDim.x + blockIdx.x;
  int cpx = nwg >> 3;
  int sw = (bid & 7) * cpx + (bid >> 3);
  int bx = sw % gridDim.x, by = sw / gridDim.x;
  const int bm = by * 256, bn = bx * 256;

  // staging coords: 4 threads per 64B row; rows tid>>2 and +128
  const int r0s = tid >> 2;        // 0..127
  const int ks = tid & 3;          // 16B granule within 64B row
  const int r1s = r0s + 128;

  auto stageA = [&](const ushort* Ap, int kg, int so) {
    __builtin_amdgcn_global_load_lds(
        (const __attribute__((address_space(1))) void*)(Ap + (size_t)(bm + r0s) * 2048 + kg + ks * 8),
        (__attribute__((address_space(3))) void*)(lds + so + r0s * 32), 16, 0, 0);
    __builtin_amdgcn_global_load_lds(
        (const __attribute__((address_space(1))) void*)(Ap + (size_t)(bm + r1s) * 2048 + kg + ks * 8),
        (__attribute__((address_space(3))) void*)(lds + so + r1s * 32), 16, 0, 0);
  };
  auto stageB = [&](const ushort* Bp, int kg, int so) {
    __builtin_amdgcn_global_load_lds(
        (const __attribute__((address_space(1))) void*)(Bp + (size_t)(bn + r0s) * 2048 + kg + ks * 8),
        (__attribute__((address_space(3))) void*)(lds + 32768 + so + r0s * 32), 16, 0, 0);
    __builtin_amdgcn_global_load_lds(
        (const __attribute__((address_space(1))) void*)(Bp + (size_t)(bn + r1s) * 2048 + kg + ks * 8),
        (__attribute__((address_space(3))) void*)(lds + 32768 + so + r1s * 32), 16, 0, 0);
  };
  auto segA = [&](int t) -> const ushort* {
    int ai = (apack >> (2 * (t >> 6))) & 3;
    return ai == 0 ? A0 : (ai == 1 ? A1 : A2);
  };
  auto segB = [&](int t) -> const ushort* {
    int bi = (bpack >> (2 * (t >> 6))) & 3;
    return bi == 0 ? B0 : (bi == 1 ? B1 : B2);
  };

  f32x4 acc[8][4];
#pragma unroll
  for (int i = 0; i < 8; ++i)
#pragma unroll
    for (int j = 0; j < 4; ++j)
      acc[i][j] = (f32x4){0.f, 0.f, 0.f, 0.f};

  const int NT = P * 64;   // K-tiles of 32; K=2048 -> 64 per pass

  // prologue: stage tiles 0,1,2 (12 loads); vmcnt(8) -> tile 0 landed
  for (int tt = 0; tt < 3; ++tt) {
    stageA(segA(tt), tt * 32, tt * 8192);
    stageB(segB(tt), tt * 32, tt * 8192);
  }
  asm volatile("s_waitcnt vmcnt(8)" ::: "memory");
  asm volatile("s_barrier" ::: "memory");

  const int aoff = wm * 4096 + lane15 * 32 + s2 * 8;   // + i*512
  const int boff = wn * 2048 + lane15 * 32 + s2 * 8;   // + j*512

  for (int t = 0; t < NT; ++t) {
    const int so = (t & 3) * 8192;
    const ushort* Ab = lds + so;
    const ushort* Bb = lds + 32768 + so;

    // staged tile: t+3, dummy-clamped to keep the vmcnt ledger uniform
    int ts = t + 3;
    if (ts > NT - 1) ts = NT - 1;
    const int sdst = ((t + 3) & 3) * 8192;   // dead slot (== (t-1)&3)
    const int kgn = (ts & 63) * 32;
    const ushort* An = segA(ts);
    const ushort* Bn = segB(ts);

    bf16x8 aa[4], bb[4];
#pragma unroll
    for (int i = 0; i < 4; ++i) aa[i] = *(const bf16x8*)(Ab + aoff + i * 512);
#pragma unroll
    for (int j = 0; j < 4; ++j) bb[j] = *(const bf16x8*)(Bb + boff + j * 512);
    stageA(An, kgn, sdst);
    __builtin_amdgcn_s_setprio(1);
#pragma unroll
    for (int i = 0; i < 4; ++i)
#pragma unroll
      for (int j = 0; j < 4; ++j)
        acc[i][j] = __builtin_amdgcn_mfma_f32_16x16x32_bf16(aa[i], bb[j], acc[i][j], 0, 0, 0);
    __builtin_amdgcn_s_setprio(0);

#pragma unroll
    for (int i = 0; i < 4; ++i) aa[i] = *(const bf16x8*)(Ab + aoff + 2048 + i * 512);
    stageB(Bn, kgn, sdst);
    __builtin_amdgcn_s_setprio(1);
#pragma unroll
    for (int i = 0; i < 4; ++i)
#pragma unroll
      for (int j = 0; j < 4; ++j)
        acc[4 + i][j] = __builtin_amdgcn_mfma_f32_16x16x32_bf16(aa[i], bb[j], acc[4 + i][j], 0, 0, 0);
    __builtin_amdgcn_s_setprio(0);

    if (t < NT - 1) {
      asm volatile("s_waitcnt vmcnt(8)" ::: "memory");  // tile t+1 landed (all my loads)
      asm volatile("s_barrier" ::: "memory");           // ... and everyone else's
    }
  }
  asm volatile("s_waitcnt vmcnt(0)" ::: "memory");  // drain dummy stages

  // epilogue: C/D layout col = lane&15, row = (lane>>4)*4 + reg
#pragma unroll
  for (int i = 0; i < 8; ++i) {
    int r0 = bm + wm * 128 + i * 16 + lhi * 4;
#pragma unroll
    for (int j = 0; j < 4; ++j) {
      int col = bn + wn * 64 + j * 16 + lane15;
      f32x4 v = acc[i][j];
      if (accum) {
#pragma unroll
        for (int r = 0; r < 4; ++r) {
          size_t idx = (size_t)(r0 + r) * N + col;
          C[idx] = C[idx] + v[r];
        }
      } else {
#pragma unroll
        for (int r = 0; r < 4; ++r)
          C[(size_t)(r0 + r) * N + col] = v[r];
      }
    }
  }
}

// ---------------------------------------------------------------------------
// LIF scan: cur = buf[idx] + bias[n] (single rounding). Writes spikes as bf16
// {0,1} in the swizzled layout; mode selects the pre-swizzle variant.
// ---------------------------------------------------------------------------
__global__ __launch_bounds__(256) void lif_spk_swz(
    const float* __restrict__ cur, const float* __restrict__ bias,
    ushort* __restrict__ spk, int N, int total, int mode)
{
  int g = blockIdx.x * 256 + threadIdx.x;
  if (g >= total) return;
  int b = g / N, n = g - b * N;
  int nb = n >> 6;
  int slot = (n >> 3) & 7;
  int nlow = n & 7;
  float bv = bias[n];
  float mem = 0.f;
  for (int t = 0; t < T_; ++t) {
    int m = b * T_ + t;
    float c = __fadd_rn(cur[(size_t)m * N + n], bv);
    float reset = ((mem - 1.0f) > 0.0f) ? 1.0f : 0.0f;
    mem = __fmul_rn(BETA, mem);
    mem = __fadd_rn(mem, c);
    mem = __fadd_rn(mem, -reset);
    ushort sv = ((mem - 1.0f) > 0.0f) ? (ushort)0x3F80 : (ushort)0;
    int ps = mode ? ((slot & 4) | ((slot & 3) ^ ((m >> 1) & 3)))
                  : (slot ^ (m & 7));
    spk[(size_t)m * N + (nb << 6) + (ps << 3) + nlow] = sv;
  }
}

__global__ __launch_bounds__(256) void lif_final(
    const float* __restrict__ cur_in, const float* __restrict__ bias,
    float* __restrict__ spk_out, float* __restrict__ mem_out, int N, int total)
{
  int g = blockIdx.x * 256 + threadIdx.x;
  if (g >= total) return;
  int b = g / N, n = g - b * N;
  size_t base = (size_t)b * T_ * N + n;
  float bv = bias[n];
  float mem = 0.f;
  for (int t = 0; t < T_; ++t) {
    size_t idx = base + (size_t)t * N;
    float c = __fadd_rn(cur_in[idx], bv);
    float reset = ((mem - 1.0f) > 0.0f) ? 1.0f : 0.0f;
    mem = __fmul_rn(BETA, mem);
    mem = __fadd_rn(mem, c);
    mem = __fadd_rn(mem, -reset);
    spk_out[idx] = ((mem - 1.0f) > 0.0f) ? 1.0f : 0.0f;
    mem_out[idx] = mem;
  }
}

extern "C" void kernel_launch(void* const* d_in, const int* in_sizes, int n_in,
                              void* d_out, int out_size, void* d_ws, size_t ws_size,
                              hipStream_t stream)
{
  const float* x  = (const float*)d_in[0];
  const float* W0 = (const float*)d_in[1];
  const float* b0 = (const float*)d_in[2];
  const float* W1 = (const float*)d_in[3];
  const float* b1 = (const float*)d_in[4];
  const float* W2 = (const float*)d_in[5];
  const float* b2 = (const float*)d_in[6];
  const float* W3 = (const float*)d_in[7];
  const float* b3 = (const float*)d_in[8];
  float* out = (float*)d_out;

  char* ws = (char*)d_ws;
  size_t off = 0;
  auto take = [&](size_t bytes) -> char* {
    char* p = ws + off;
    off += (bytes + 255) & ~(size_t)255;
    return p;
  };

  ushort* w0s[3], *w1s[3], *w2s[3], *w3s[3], *xs[3];
  for (int i = 0; i < 3; ++i) w0s[i] = (ushort*)take((size_t)2048 * 2048 * 2);
  for (int i = 0; i < 3; ++i) w1s[i] = (ushort*)take((size_t)2048 * 2048 * 2);
  for (int i = 0; i < 3; ++i) w2s[i] = (ushort*)take((size_t)1024 * 2048 * 2);
  for (int i = 0; i < 3; ++i) w3s[i] = (ushort*)take((size_t)128 * 1024 * 2);
  for (int i = 0; i < 3; ++i) xs[i]  = (ushort*)take((size_t)M_ * 2048 * 2);
  float* cur = (float*)take((size_t)M_ * 2048 * 4);
  // spike buffers alias the x-split region (dead after L0 GEMMs)
  ushort* s0 = xs[0];
  ushort* s1 = xs[1];
  ushort* s2 = xs[2];

  dim3 blk(256);

  // --- splits: mode 1 (gemm256 operands): x, W0, W1; mode 0: W2, W3 ---
  {
    int ns = 2048 * 2048 / 8;
    split3_swz<<<(ns + 255) / 256, blk, 0, stream>>>(W0, w0s[0], w0s[1], w0s[2], 2048, ns, 1);
    split3_swz<<<(ns + 255) / 256, blk, 0, stream>>>(W1, w1s[0], w1s[1], w1s[2], 2048, ns, 1);
    ns = 1024 * 2048 / 8;
    split3_swz<<<(ns + 255) / 256, blk, 0, stream>>>(W2, w2s[0], w2s[1], w2s[2], 2048, ns, 0);
    ns = 128 * 1024 / 8;
    split3_swz<<<(ns + 255) / 256, blk, 0, stream>>>(W3, w3s[0], w3s[1], w3s[2], 1024, ns, 0);
    ns = M_ * 2048 / 8;
    split3_swz<<<(ns + 255) / 256, blk, 0, stream>>>(x, xs[0], xs[1], xs[2], 2048, ns, 1);
  }

  // --- L0 (gemm256): main x1w1; corr chain x1w2,x2w1,x1w3,x2w2,x3w1 ---
  {
    dim3 grid(2048 / 256, M_ / 256);  // (8, 32)
    gemm256<<<grid, dim3(512), 0, stream>>>(xs[0], xs[1], xs[2], w0s[0], w0s[1], w0s[2],
                                            1, 0, 0, 2048, 0, cur);
    int apack = 0 | (1 << 2) | (0 << 4) | (1 << 6) | (2 << 8);
    int bpack = 1 | (0 << 2) | (2 << 4) | (1 << 6) | (0 << 8);
    gemm256<<<grid, dim3(512), 0, stream>>>(xs[0], xs[1], xs[2], w0s[0], w0s[1], w0s[2],
                                            5, apack, bpack, 2048, 1, cur);
    lif_spk_swz<<<(B_ * 2048) / 256, blk, 0, stream>>>(cur, b0, s0, 2048, B_ * 2048, 1);
  }
  // --- L1 (gemm256): main s0@w1; corr s0@w2, s0@w3 ---
  {
    dim3 grid(2048 / 256, M_ / 256);
    gemm256<<<grid, dim3(512), 0, stream>>>(s0, s0, s0, w1s[0], w1s[1], w1s[2],
                                            1, 0, 0, 2048, 0, cur);
    gemm256<<<grid, dim3(512), 0, stream>>>(s0, s0, s0, w1s[0], w1s[1], w1s[2],
                                            2, 0, 1 | (2 << 2), 2048, 1, cur);
    lif_spk_swz<<<(B_ * 2048) / 256, blk, 0, stream>>>(cur, b1, s1, 2048, B_ * 2048, 0);
  }
  // --- L2 (gemm_seg, mode-0 operands) ---
  {
    dim3 grid(1024 / 128, M_ / 128);
    gemm_seg<<<grid, blk, 0, stream>>>(s1, s1, s1, w2s[0], w2s[1], w2s[2],
                                       1, 0, 0, 2048, 1024, 0, cur);
    gemm_seg<<<grid, blk, 0, stream>>>(s1, s1, s1, w2s[0], w2s[1], w2s[2],
                                       2, 0, 1 | (2 << 2), 2048, 1024, 1, cur);
    lif_spk_swz<<<(B_ * 1024) / 256, blk, 0, stream>>>(cur, b2, s2, 1024, B_ * 1024, 0);
  }
  // --- L3 (gemm_seg) + final LIF ---
  {
    dim3 grid(128 / 128, M_ / 128);
    gemm_seg<<<grid, blk, 0, stream>>>(s2, s2, s2, w3s[0], w3s[1], w3s[2],
                                       1, 0, 0, 1024, 128, 0, cur);
    gemm_seg<<<grid, blk, 0, stream>>>(s2, s2, s2, w3s[0], w3s[1], w3s[2],
                                       2, 0, 1 | (2 << 2), 1024, 128, 1, cur);
    float* spk3 = out;
    float* mem3 = out + (size_t)M_ * NOUT;
    lif_final<<<(B_ * NOUT) / 256, blk, 0, stream>>>(cur, b3, spk3, mem3, NOUT, B_ * NOUT);
  }
}